// Round 7
// baseline (196.467 us; speedup 1.0000x reference)
//
#include <hip/hip_runtime.h>

// ---------- types ----------
typedef __attribute__((ext_vector_type(4))) float  f32x4;
typedef __attribute__((ext_vector_type(8))) short  s16x8;   // 8 bf16 (4 VGPRs)
typedef __attribute__((ext_vector_type(8))) unsigned short u16x8;
typedef __attribute__((ext_vector_type(4))) unsigned short u16x4;

static __device__ __forceinline__ unsigned short f2bf(float f) {
    unsigned int u = __builtin_bit_cast(unsigned int, f);
    u += 0x7fffu + ((u >> 16) & 1u);      // round-to-nearest-even
    return (unsigned short)(u >> 16);
}

static __device__ __forceinline__ unsigned int cvt_pk_bf16(float lo, float hi) {
    unsigned int r;
    asm("v_cvt_pk_bf16_f32 %0, %1, %2" : "=v"(r) : "v"(lo), "v"(hi));
    return r;
}

static __device__ __forceinline__ void gload16(const void* g, void* l) {
    __builtin_amdgcn_global_load_lds(
        (const __attribute__((address_space(1))) void*)g,
        (__attribute__((address_space(3))) void*)l, 16, 0, 0);
}

// =====================================================================
// fp32 -> bf16 convert pass: q,k,v + 4 weights. 2048 elems/block.
// =====================================================================
__global__ __launch_bounds__(256)
void conv_kernel(const float* __restrict__ q, const float* __restrict__ k,
                 const float* __restrict__ v,
                 const float* __restrict__ wq, const float* __restrict__ wk,
                 const float* __restrict__ wv, const float* __restrict__ wo,
                 unsigned short* __restrict__ qb, unsigned short* __restrict__ kb,
                 unsigned short* __restrict__ vb, unsigned short* __restrict__ wb)
{
    const int bid = blockIdx.x;
    const float* src; unsigned short* dst; int inner;
    if      (bid < 4096)  { src = q;  dst = qb; inner = bid; }
    else if (bid < 8192)  { src = k;  dst = kb; inner = bid - 4096; }
    else if (bid < 12288) { src = v;  dst = vb; inner = bid - 8192; }
    else {
        const int wseg = (bid - 12288) >> 9;
        src = wseg == 0 ? wq : wseg == 1 ? wk : wseg == 2 ? wv : wo;
        dst = wb + (size_t)wseg * 1048576;
        inner = (bid - 12288) & 511;
    }
    const size_t e0 = (size_t)inner * 2048 + threadIdx.x * 8;
    f32x4 a = *(const f32x4*)(src + e0);
    f32x4 b = *(const f32x4*)(src + e0 + 4);
    u16x8 o;
    #pragma unroll
    for (int i = 0; i < 4; ++i) { o[i] = f2bf(a[i]); o[i + 4] = f2bf(b[i]); }
    *(u16x8*)(dst + e0) = o;
}

// =====================================================================
// bf16 NT GEMM, 256x128 tile, BK=64, 8 waves (4M x 2N, 64x64 each),
// ring-3 LDS (144 KB), 2-tiles-ahead staging, 8-PHASE schedule:
// per K-tile 4 phases, each {ds_read subtile || 1-2 gload_lds(t+2)
//   -> s_barrier -> lgkmcnt(0) -> setprio(1) 8xMFMA setprio(0)
//   -> s_barrier}; ONE counted vmcnt(6) per K-tile (phase 4).
// EPI 0: fused QKV. grid 768. seg0->Qh*0.125 ; seg1->Kh ; seg2->Vt
// EPI 1: out proj. grid 256. Of fp32 [8192,1024].
// =====================================================================
template<int EPI>
__global__ __launch_bounds__(512)
void gemm8(const unsigned short* __restrict__ A0,
           const unsigned short* __restrict__ A1,
           const unsigned short* __restrict__ A2,
           const unsigned short* __restrict__ Bw,
           unsigned short* __restrict__ O0, unsigned short* __restrict__ O1,
           unsigned short* __restrict__ O2, float* __restrict__ Of)
{
    __shared__ unsigned short Asw[3][256 * 64];   // 96 KB
    __shared__ unsigned short Bsw[3][128 * 64];   // 48 KB

    const int tid  = threadIdx.x;
    const int lane = tid & 63;
    const int wave = tid >> 6;
    const int wr   = wave >> 1, wc = wave & 1;    // 4M x 2N waves
    const int g    = lane >> 4, l16 = lane & 15;

    const int nblk = (EPI == 0) ? 768 : 256;
    const int cpx  = nblk >> 3;
    const int wg   = (blockIdx.x & 7) * cpx + (blockIdx.x >> 3);  // bijective XCD swizzle
    const int bx   = wg & 7;
    const int byt  = wg >> 3;
    const int seg  = (EPI == 0) ? (byt >> 5) : 0;
    const int byl  = (EPI == 0) ? (byt & 31) : byt;

    const unsigned short* Ap = (EPI == 0) ? (seg == 0 ? A0 : seg == 1 ? A1 : A2) : A0;
    const unsigned short* Arow = Ap + (size_t)(byl * 256) * 1024;
    const unsigned short* Brow = Bw + (size_t)seg * 1048576 + (size_t)(bx * 128) * 1024;

    f32x4 acc[4][4] = {};

    // one 16B gload_lds chunk: linear LDS dest, inverse-swizzled global source.
    auto stageA = [&](int buf, int kt2, int j) {
        const int idx = j * 512 + tid;
        const int r   = idx >> 3;
        const int cl  = (tid & 7) ^ (r & 7);
        gload16(Arow + (size_t)r * 1024 + kt2 * 64 + cl * 8,
                (char*)Asw[buf] + j * 8192 + wave * 1024);
    };
    auto stageB = [&](int buf, int kt2, int j) {
        const int idx = j * 512 + tid;
        const int r   = idx >> 3;
        const int cl  = (tid & 7) ^ (r & 7);
        gload16(Brow + (size_t)r * 1024 + kt2 * 64 + cl * 8,
                (char*)Bsw[buf] + j * 8192 + wave * 1024);
    };
    auto lda = [&](const char* Ab, int mi, int ks) -> s16x8 {
        const int row = wr * 64 + mi * 16 + l16;
        const int off = (row * 128 + g * 16 + ks * 64) ^ ((row & 7) << 4);
        return __builtin_bit_cast(s16x8, *(const u16x8*)(Ab + off));
    };
    auto ldb = [&](const char* Bb, int ni, int ks) -> s16x8 {
        const int row = wc * 64 + ni * 16 + l16;
        const int off = (row * 128 + g * 16 + ks * 64) ^ ((row & 7) << 4);
        return __builtin_bit_cast(s16x8, *(const u16x8*)(Bb + off));
    };

    // prologue: tiles 0 and 1 in flight; wait tile 0 (newest 6 = tile 1).
    #pragma unroll
    for (int j = 0; j < 4; ++j) stageA(0, 0, j);
    #pragma unroll
    for (int j = 0; j < 2; ++j) stageB(0, 0, j);
    #pragma unroll
    for (int j = 0; j < 4; ++j) stageA(1, 1, j);
    #pragma unroll
    for (int j = 0; j < 2; ++j) stageB(1, 1, j);
    asm volatile("s_waitcnt vmcnt(6)" ::: "memory");
    __builtin_amdgcn_s_barrier();

    for (int kt = 0; kt < 16; ++kt) {
        const char* Ab = (const char*)Asw[kt % 3];
        const char* Bb = (const char*)Bsw[kt % 3];
        const bool st  = (kt + 2 < 16);
        const int  sb  = (kt + 2) % 3;
        const int  kn  = kt + 2;
        s16x8 a0, a1, a2, a3, b0, b1, b2, b3;

        // ---- phase 0: B(ks0) x4 + A(ks0) mi0,1 ; stage A j0,j1 ----
        b0 = ldb(Bb, 0, 0); b1 = ldb(Bb, 1, 0); b2 = ldb(Bb, 2, 0); b3 = ldb(Bb, 3, 0);
        a0 = lda(Ab, 0, 0); a1 = lda(Ab, 1, 0);
        if (st) { stageA(sb, kn, 0); stageA(sb, kn, 1); }
        __builtin_amdgcn_sched_barrier(0);
        __builtin_amdgcn_s_barrier();
        asm volatile("s_waitcnt lgkmcnt(0)" ::: "memory");
        __builtin_amdgcn_sched_barrier(0);
        __builtin_amdgcn_s_setprio(1);
        acc[0][0] = __builtin_amdgcn_mfma_f32_16x16x32_bf16(a0, b0, acc[0][0], 0, 0, 0);
        acc[0][1] = __builtin_amdgcn_mfma_f32_16x16x32_bf16(a0, b1, acc[0][1], 0, 0, 0);
        acc[0][2] = __builtin_amdgcn_mfma_f32_16x16x32_bf16(a0, b2, acc[0][2], 0, 0, 0);
        acc[0][3] = __builtin_amdgcn_mfma_f32_16x16x32_bf16(a0, b3, acc[0][3], 0, 0, 0);
        acc[1][0] = __builtin_amdgcn_mfma_f32_16x16x32_bf16(a1, b0, acc[1][0], 0, 0, 0);
        acc[1][1] = __builtin_amdgcn_mfma_f32_16x16x32_bf16(a1, b1, acc[1][1], 0, 0, 0);
        acc[1][2] = __builtin_amdgcn_mfma_f32_16x16x32_bf16(a1, b2, acc[1][2], 0, 0, 0);
        acc[1][3] = __builtin_amdgcn_mfma_f32_16x16x32_bf16(a1, b3, acc[1][3], 0, 0, 0);
        __builtin_amdgcn_s_setprio(0);
        __builtin_amdgcn_sched_barrier(0);
        __builtin_amdgcn_s_barrier();

        // ---- phase 1: A(ks0) mi2,3 ; stage A j2,j3 ----
        a2 = lda(Ab, 2, 0); a3 = lda(Ab, 3, 0);
        if (st) { stageA(sb, kn, 2); stageA(sb, kn, 3); }
        __builtin_amdgcn_sched_barrier(0);
        __builtin_amdgcn_s_barrier();
        asm volatile("s_waitcnt lgkmcnt(0)" ::: "memory");
        __builtin_amdgcn_sched_barrier(0);
        __builtin_amdgcn_s_setprio(1);
        acc[2][0] = __builtin_amdgcn_mfma_f32_16x16x32_bf16(a2, b0, acc[2][0], 0, 0, 0);
        acc[2][1] = __builtin_amdgcn_mfma_f32_16x16x32_bf16(a2, b1, acc[2][1], 0, 0, 0);
        acc[2][2] = __builtin_amdgcn_mfma_f32_16x16x32_bf16(a2, b2, acc[2][2], 0, 0, 0);
        acc[2][3] = __builtin_amdgcn_mfma_f32_16x16x32_bf16(a2, b3, acc[2][3], 0, 0, 0);
        acc[3][0] = __builtin_amdgcn_mfma_f32_16x16x32_bf16(a3, b0, acc[3][0], 0, 0, 0);
        acc[3][1] = __builtin_amdgcn_mfma_f32_16x16x32_bf16(a3, b1, acc[3][1], 0, 0, 0);
        acc[3][2] = __builtin_amdgcn_mfma_f32_16x16x32_bf16(a3, b2, acc[3][2], 0, 0, 0);
        acc[3][3] = __builtin_amdgcn_mfma_f32_16x16x32_bf16(a3, b3, acc[3][3], 0, 0, 0);
        __builtin_amdgcn_s_setprio(0);
        __builtin_amdgcn_sched_barrier(0);
        __builtin_amdgcn_s_barrier();

        // ---- phase 2: B(ks1) x4 + A(ks1) mi0,1 ; stage B j0 ----
        b0 = ldb(Bb, 0, 1); b1 = ldb(Bb, 1, 1); b2 = ldb(Bb, 2, 1); b3 = ldb(Bb, 3, 1);
        a0 = lda(Ab, 0, 1); a1 = lda(Ab, 1, 1);
        if (st) { stageB(sb, kn, 0); }
        __builtin_amdgcn_sched_barrier(0);
        __builtin_amdgcn_s_barrier();
        asm volatile("s_waitcnt lgkmcnt(0)" ::: "memory");
        __builtin_amdgcn_sched_barrier(0);
        __builtin_amdgcn_s_setprio(1);
        acc[0][0] = __builtin_amdgcn_mfma_f32_16x16x32_bf16(a0, b0, acc[0][0], 0, 0, 0);
        acc[0][1] = __builtin_amdgcn_mfma_f32_16x16x32_bf16(a0, b1, acc[0][1], 0, 0, 0);
        acc[0][2] = __builtin_amdgcn_mfma_f32_16x16x32_bf16(a0, b2, acc[0][2], 0, 0, 0);
        acc[0][3] = __builtin_amdgcn_mfma_f32_16x16x32_bf16(a0, b3, acc[0][3], 0, 0, 0);
        acc[1][0] = __builtin_amdgcn_mfma_f32_16x16x32_bf16(a1, b0, acc[1][0], 0, 0, 0);
        acc[1][1] = __builtin_amdgcn_mfma_f32_16x16x32_bf16(a1, b1, acc[1][1], 0, 0, 0);
        acc[1][2] = __builtin_amdgcn_mfma_f32_16x16x32_bf16(a1, b2, acc[1][2], 0, 0, 0);
        acc[1][3] = __builtin_amdgcn_mfma_f32_16x16x32_bf16(a1, b3, acc[1][3], 0, 0, 0);
        __builtin_amdgcn_s_setprio(0);
        __builtin_amdgcn_sched_barrier(0);
        __builtin_amdgcn_s_barrier();

        // ---- phase 3: A(ks1) mi2,3 ; stage B j1 ; counted vmcnt ----
        a2 = lda(Ab, 2, 1); a3 = lda(Ab, 3, 1);
        if (st) { stageB(sb, kn, 1); }
        __builtin_amdgcn_sched_barrier(0);
        __builtin_amdgcn_s_barrier();
        asm volatile("s_waitcnt lgkmcnt(0)" ::: "memory");
        __builtin_amdgcn_sched_barrier(0);
        __builtin_amdgcn_s_setprio(1);
        acc[2][0] = __builtin_amdgcn_mfma_f32_16x16x32_bf16(a2, b0, acc[2][0], 0, 0, 0);
        acc[2][1] = __builtin_amdgcn_mfma_f32_16x16x32_bf16(a2, b1, acc[2][1], 0, 0, 0);
        acc[2][2] = __builtin_amdgcn_mfma_f32_16x16x32_bf16(a2, b2, acc[2][2], 0, 0, 0);
        acc[2][3] = __builtin_amdgcn_mfma_f32_16x16x32_bf16(a2, b3, acc[2][3], 0, 0, 0);
        acc[3][0] = __builtin_amdgcn_mfma_f32_16x16x32_bf16(a3, b0, acc[3][0], 0, 0, 0);
        acc[3][1] = __builtin_amdgcn_mfma_f32_16x16x32_bf16(a3, b1, acc[3][1], 0, 0, 0);
        acc[3][2] = __builtin_amdgcn_mfma_f32_16x16x32_bf16(a3, b2, acc[3][2], 0, 0, 0);
        acc[3][3] = __builtin_amdgcn_mfma_f32_16x16x32_bf16(a3, b3, acc[3][3], 0, 0, 0);
        __builtin_amdgcn_s_setprio(0);
        if (st)                asm volatile("s_waitcnt vmcnt(6)" ::: "memory");
        else if (kt + 1 < 16)  asm volatile("s_waitcnt vmcnt(0)" ::: "memory");
        __builtin_amdgcn_sched_barrier(0);
        __builtin_amdgcn_s_barrier();
    }

    // ---- epilogue ----
    #pragma unroll
    for (int mi = 0; mi < 4; ++mi) {
        #pragma unroll
        for (int ni = 0; ni < 4; ++ni) {
            const int gr0 = byl * 256 + wr * 64 + mi * 16 + g * 4;
            const int gc  = bx * 128 + wc * 64 + ni * 16 + l16;
            if (EPI == 0 && seg == 2) {
                const int b = gr0 >> 11, ll = gr0 & 2047;
                const int h = gc >> 6,  dh = gc & 63;
                u16x4 pk;
                #pragma unroll
                for (int rr = 0; rr < 4; ++rr) pk[rr] = f2bf(acc[mi][ni][rr]);
                *(u16x4*)(O2 + (size_t)((b * 16 + h) * 64 + dh) * 2048 + ll) = pk;
            } else {
                #pragma unroll
                for (int rr = 0; rr < 4; ++rr) {
                    const int gr = gr0 + rr;
                    float v = acc[mi][ni][rr];
                    if (EPI == 0) {
                        const int b = gr >> 11, ll = gr & 2047;
                        const int h = gc >> 6,  dh = gc & 63;
                        if (seg == 0) {
                            v *= 0.125f;
                            O0[(size_t)((b * 16 + h) * 2048 + ll) * 64 + dh] = f2bf(v);
                        } else {
                            O1[(size_t)((b * 16 + h) * 2048 + ll) * 64 + dh] = f2bf(v);
                        }
                    } else {
                        Of[(size_t)gr * 1024 + gc] = v;
                    }
                }
            }
        }
    }
}

// =====================================================================
// Fallback GEMM (fp32 inputs converted in-loop) — only used if ws too small.
// =====================================================================
template<int AM, int BM, int EPI>
__global__ __launch_bounds__(256)
void gemm_k(const void* __restrict__ A0, const void* __restrict__ A1,
            const void* __restrict__ A2,
            const void* __restrict__ B0, const void* __restrict__ B1,
            const void* __restrict__ B2,
            unsigned short* __restrict__ O0, unsigned short* __restrict__ O1,
            unsigned short* __restrict__ O2, float* __restrict__ Of)
{
    __shared__ unsigned short Asw[128 * 64];
    __shared__ unsigned short Bsw[128 * 64];

    const int tid  = threadIdx.x;
    const int lane = tid & 63;
    const int wave = tid >> 6;
    const int wr   = wave >> 1, wc = wave & 1;
    const int g    = lane >> 4, l16 = lane & 15;

    const int nper = (EPI == 0) ? 192 : 64;
    const int wg   = (blockIdx.x & 7) * nper + (blockIdx.x >> 3);
    const int bx   = wg & 7;
    const int by   = wg >> 3;
    const int seg  = (EPI == 0) ? (by >> 6) : 0;
    const int byl  = (EPI == 0) ? (by & 63) : by;

    const void* Ap = seg == 0 ? A0 : seg == 1 ? A1 : A2;
    const void* Bp = seg == 0 ? B0 : seg == 1 ? B1 : B2;

    f32x4 acc[4][4] = {};

    for (int kt = 0; kt < 16; ++kt) {
        __syncthreads();
        if (AM == 0) {
            #pragma unroll
            for (int j = 0; j < 4; ++j) {
                const int idx = j * 256 + tid;
                const int r   = idx >> 3;
                const int cl  = (tid & 7) ^ (r & 7);
                gload16((const unsigned short*)Ap + (size_t)(byl * 128 + r) * 1024 + kt * 64 + cl * 8,
                        (char*)Asw + j * 4096 + wave * 1024);
            }
        } else {
            #pragma unroll
            for (int j = 0; j < 4; ++j) {
                const int idx = j * 256 + tid;
                const int r = idx >> 3, c = tid & 7;
                const float* src = (const float*)Ap + (size_t)(byl * 128 + r) * 1024 + kt * 64 + c * 8;
                f32x4 a = *(const f32x4*)src;
                f32x4 b = *(const f32x4*)(src + 4);
                u16x8 w;
                #pragma unroll
                for (int i = 0; i < 4; ++i) { w[i] = f2bf(a[i]); w[i + 4] = f2bf(b[i]); }
                *(u16x8*)((char*)Asw + ((r * 128 + c * 16) ^ ((r & 7) << 4))) = w;
            }
        }
        if (BM == 0) {
            #pragma unroll
            for (int j = 0; j < 4; ++j) {
                const int idx = j * 256 + tid;
                const int r   = idx >> 3;
                const int cl  = (tid & 7) ^ (r & 7);
                gload16((const unsigned short*)Bp + (size_t)(bx * 128 + r) * 1024 + kt * 64 + cl * 8,
                        (char*)Bsw + j * 4096 + wave * 1024);
            }
        } else {
            #pragma unroll
            for (int j = 0; j < 4; ++j) {
                const int idx = j * 256 + tid;
                const int r = idx >> 3, c = tid & 7;
                const float* src = (const float*)Bp + (size_t)(bx * 128 + r) * 1024 + kt * 64 + c * 8;
                f32x4 a = *(const f32x4*)src;
                f32x4 b = *(const f32x4*)(src + 4);
                u16x8 w;
                #pragma unroll
                for (int i = 0; i < 4; ++i) { w[i] = f2bf(a[i]); w[i + 4] = f2bf(b[i]); }
                *(u16x8*)((char*)Bsw + ((r * 128 + c * 16) ^ ((r & 7) << 4))) = w;
            }
        }
        __syncthreads();

        #pragma unroll
        for (int ks = 0; ks < 2; ++ks) {
            s16x8 af[4], bf[4];
            #pragma unroll
            for (int mi = 0; mi < 4; ++mi) {
                const int row = wr * 64 + mi * 16 + l16;
                const int off = (row * 128 + g * 16 + ks * 64) ^ ((row & 7) << 4);
                af[mi] = __builtin_bit_cast(s16x8, *(const u16x8*)((const char*)Asw + off));
            }
            #pragma unroll
            for (int ni = 0; ni < 4; ++ni) {
                const int row = wc * 64 + ni * 16 + l16;
                const int off = (row * 128 + g * 16 + ks * 64) ^ ((row & 7) << 4);
                bf[ni] = __builtin_bit_cast(s16x8, *(const u16x8*)((const char*)Bsw + off));
            }
            #pragma unroll
            for (int mi = 0; mi < 4; ++mi)
                #pragma unroll
                for (int ni = 0; ni < 4; ++ni)
                    acc[mi][ni] = __builtin_amdgcn_mfma_f32_16x16x32_bf16(
                        af[mi], bf[ni], acc[mi][ni], 0, 0, 0);
        }
    }

    #pragma unroll
    for (int mi = 0; mi < 4; ++mi) {
        #pragma unroll
        for (int ni = 0; ni < 4; ++ni) {
            #pragma unroll
            for (int rr = 0; rr < 4; ++rr) {
                const int gr = byl * 128 + wr * 64 + mi * 16 + g * 4 + rr;
                const int gc = bx * 128 + wc * 64 + ni * 16 + l16;
                float v = acc[mi][ni][rr];
                if (EPI == 0) {
                    const int b = gr >> 11, ll = gr & 2047, h = gc >> 6, dh = gc & 63;
                    if (seg == 0) {
                        v *= 0.125f;
                        O0[(size_t)((b * 16 + h) * 2048 + ll) * 64 + dh] = f2bf(v);
                    } else if (seg == 1) {
                        O1[(size_t)((b * 16 + h) * 2048 + ll) * 64 + dh] = f2bf(v);
                    } else {
                        O2[(size_t)((b * 16 + h) * 64 + dh) * 2048 + ll] = f2bf(v);
                    }
                } else {
                    Of[(size_t)gr * 1024 + gc] = v;
                }
            }
        }
    }
}

// =====================================================================
// Flash-style causal attention, double-buffered KV.
// Swapped QK^T (S^T = mfma(K,Q)) -> per-lane row softmax (q = l16),
// defer-max (THR=8), cvt_pk P->bf16, b64 P writes.  (unchanged)
// =====================================================================
__global__ __launch_bounds__(512)
void attn_kernel(const unsigned short* __restrict__ Qh,
                 const unsigned short* __restrict__ Kh,
                 const unsigned short* __restrict__ Vt,
                 unsigned short* __restrict__ Ctx)
{
    __shared__ unsigned short Ksw[2][64 * 64];
    __shared__ unsigned short Vsw[2][64 * 64];
    __shared__ unsigned short Psw[8][16 * 64];

    const int tid  = threadIdx.x;
    const int lane = tid & 63;
    const int wave = tid >> 6;
    const int g    = lane >> 4, l16 = lane & 15;
    const int qb   = 15 - (int)(blockIdx.x >> 6);
    const int bh   = blockIdx.x & 63;
    const int b    = bh >> 4, h = bh & 15;
    const int qrow0 = qb * 128 + wave * 16;
    const int ntile = 2 * qb + 2;

    const int sr = tid >> 3, sc = tid & 7;
    const int soff = (sr * 128 + sc * 16) ^ ((sr & 7) << 4);
    const unsigned short* kbase = Kh + ((size_t)bh * 2048 + sr) * 64 + sc * 8;
    const unsigned short* vbase = Vt + ((size_t)bh * 64 + sr) * 2048 + sc * 8;

    s16x8 qf[2];
    {
        const unsigned short* qp = Qh + ((size_t)bh * 2048 + qrow0 + l16) * 64 + g * 8;
        qf[0] = __builtin_bit_cast(s16x8, *(const u16x8*)qp);
        qf[1] = __builtin_bit_cast(s16x8, *(const u16x8*)(qp + 32));
    }

    f32x4 o[4] = {};
    float m = -3.0e38f, l = 0.f;   // per-lane row state: q = l16

    *(u16x8*)((char*)Ksw[0] + soff) = *(const u16x8*)kbase;
    *(u16x8*)((char*)Vsw[0] + soff) = *(const u16x8*)vbase;
    __syncthreads();

    int cur = 0;
    for (int t = 0; t < ntile; ++t) {
        const int kv0 = t * 64;

        u16x8 kn, vn;
        const bool hn = (t + 1 < ntile);
        if (hn) {
            kn = *(const u16x8*)(kbase + (size_t)(kv0 + 64) * 64);
            vn = *(const u16x8*)(vbase + (kv0 + 64));
        }

        if (kv0 <= qrow0 + 15) {
            const char* Kb = (const char*)Ksw[cur];
            const char* Vb = (const char*)Vsw[cur];

            // ---- S^T = K Q^T : st[nt][rr] = S[kv = kv0+nt*16+g*4+rr][q = qrow0+l16]
            f32x4 st[4] = {};
            __builtin_amdgcn_s_setprio(1);
            #pragma unroll
            for (int nt = 0; nt < 4; ++nt) {
                #pragma unroll
                for (int ks = 0; ks < 2; ++ks) {
                    const int row = nt * 16 + l16;
                    const int off = (row * 128 + g * 16 + ks * 64) ^ ((row & 7) << 4);
                    s16x8 kf = __builtin_bit_cast(s16x8, *(const u16x8*)(Kb + off));
                    st[nt] = __builtin_amdgcn_mfma_f32_16x16x32_bf16(kf, qf[ks], st[nt], 0, 0, 0);
                }
            }
            __builtin_amdgcn_s_setprio(0);

            // ---- causal mask (diagonal tiles only) ----
            if (kv0 + 63 > qrow0) {
                const int q_g = qrow0 + l16;
                #pragma unroll
                for (int nt = 0; nt < 4; ++nt)
                    #pragma unroll
                    for (int rr = 0; rr < 4; ++rr) {
                        const int kv_g = kv0 + nt * 16 + g * 4 + rr;
                        if (kv_g > q_g) st[nt][rr] = -3.0e38f;
                    }
            }

            // ---- per-lane row max, reduce across g groups ----
            float pmax = fmaxf(
                fmaxf(fmaxf(fmaxf(st[0][0], st[0][1]), fmaxf(st[0][2], st[0][3])),
                      fmaxf(fmaxf(st[1][0], st[1][1]), fmaxf(st[1][2], st[1][3]))),
                fmaxf(fmaxf(fmaxf(st[2][0], st[2][1]), fmaxf(st[2][2], st[2][3])),
                      fmaxf(fmaxf(st[3][0], st[3][1]), fmaxf(st[3][2], st[3][3]))));
            pmax = fmaxf(pmax, __shfl_xor(pmax, 16));
            pmax = fmaxf(pmax, __shfl_xor(pmax, 32));

            if (__all(pmax <= m + 8.0f)) {
                float r0 = 0.f;
                #pragma unroll
                for (int nt = 0; nt < 4; ++nt)
                    #pragma unroll
                    for (int rr = 0; rr < 4; ++rr) {
                        const float p = __expf(st[nt][rr] - m);
                        st[nt][rr] = p;
                        r0 += p;
                    }
                r0 += __shfl_xor(r0, 16);
                r0 += __shfl_xor(r0, 32);
                l += r0;
            } else {
                const float mn = fmaxf(m, pmax);
                const float scf = __expf(m - mn);
                m = mn;
                float r0 = 0.f;
                #pragma unroll
                for (int nt = 0; nt < 4; ++nt)
                    #pragma unroll
                    for (int rr = 0; rr < 4; ++rr) {
                        const float p = __expf(st[nt][rr] - mn);
                        st[nt][rr] = p;
                        r0 += p;
                    }
                r0 += __shfl_xor(r0, 16);
                r0 += __shfl_xor(r0, 32);
                l = l * scf + r0;
                float sc4[4];
                #pragma unroll
                for (int rr = 0; rr < 4; ++rr) sc4[rr] = __shfl(scf, g * 4 + rr);
                #pragma unroll
                for (int nt = 0; nt < 4; ++nt)
                    #pragma unroll
                    for (int rr = 0; rr < 4; ++rr)
                        o[nt][rr] *= sc4[rr];
            }

            // ---- P -> per-wave LDS: pack pairs (consecutive kv) via cvt_pk ----
            unsigned short* Pw = Psw[wave];
            #pragma unroll
            for (int nt = 0; nt < 4; ++nt) {
                const unsigned int w0 = cvt_pk_bf16(st[nt][0], st[nt][1]);
                const unsigned int w1 = cvt_pk_bf16(st[nt][2], st[nt][3]);
                const int off = (l16 * 128 + nt * 32 + g * 8) ^ ((l16 & 7) << 4);
                const unsigned long long dw = ((unsigned long long)w1 << 32) | w0;
                *(unsigned long long*)((char*)Pw + off) = dw;
            }
            // wave-private LDS: in-order per-wave DS pipe, no barrier

            __builtin_amdgcn_s_setprio(1);
            #pragma unroll
            for (int ks = 0; ks < 2; ++ks) {
                const int offp = (l16 * 128 + g * 16 + ks * 64) ^ ((l16 & 7) << 4);
                s16x8 pf = __builtin_bit_cast(s16x8, *(const u16x8*)((const char*)Pw + offp));
                #pragma unroll
                for (int nt = 0; nt < 4; ++nt) {
                    const int row = nt * 16 + l16;
                    const int off = (row * 128 + g * 16 + ks * 64) ^ ((row & 7) << 4);
                    s16x8 vf = __builtin_bit_cast(s16x8, *(const u16x8*)(Vb + off));
                    o[nt] = __builtin_amdgcn_mfma_f32_16x16x32_bf16(pf, vf, o[nt], 0, 0, 0);
                }
            }
            __builtin_amdgcn_s_setprio(0);
        }

        if (hn) {
            *(u16x8*)((char*)Ksw[cur ^ 1] + soff) = kn;
            *(u16x8*)((char*)Vsw[cur ^ 1] + soff) = vn;
        }
        __syncthreads();
        cur ^= 1;
    }

    // ---- epilogue: o rows q = g*4+rr; l lives on lane l16 = that row ----
    #pragma unroll
    for (int rr = 0; rr < 4; ++rr) {
        const float lq = __shfl(l, g * 4 + rr);
        const float inv = 1.0f / lq;
        const int q_g = qrow0 + g * 4 + rr;
        #pragma unroll
        for (int nt = 0; nt < 4; ++nt) {
            const int d = nt * 16 + l16;
            Ctx[((size_t)b * 2048 + q_g) * 1024 + h * 64 + d] = f2bf(o[nt][rr] * inv);
        }
    }
}

// =====================================================================
extern "C" void kernel_launch(void* const* d_in, const int* in_sizes, int n_in,
                              void* d_out, int out_size, void* d_ws, size_t ws_size,
                              hipStream_t stream)
{
    const float* q  = (const float*)d_in[0];
    const float* k  = (const float*)d_in[1];
    const float* v  = (const float*)d_in[2];
    const float* Wq = (const float*)d_in[4];
    const float* Wk = (const float*)d_in[5];
    const float* Wv = (const float*)d_in[6];
    const float* Wo = (const float*)d_in[7];

    const size_t NE = (size_t)4 * 16 * 2048 * 64;
    const size_t WE = (size_t)1024 * 1024;
    unsigned short* Qh = (unsigned short*)d_ws;
    unsigned short* Kh = Qh + NE;
    unsigned short* Vt = Kh + NE;
    float* outp = (float*)d_out;
    dim3 blk(256);

    if (ws_size >= 6 * NE * 2 + 4 * WE * 2) {
        unsigned short* qb  = Vt + NE;
        unsigned short* kb  = qb + NE;
        unsigned short* vb  = kb + NE;
        unsigned short* wb  = vb + NE;
        unsigned short* Ctx = qb;
        conv_kernel<<<dim3(14336), blk, 0, stream>>>(q, k, v, Wq, Wk, Wv, Wo,
                                                     qb, kb, vb, wb);
        gemm8<0><<<dim3(768), dim3(512), 0, stream>>>(
            qb, kb, vb, wb, Qh, Kh, Vt, nullptr);
        attn_kernel<<<dim3(1024), dim3(512), 0, stream>>>(Qh, Kh, Vt, Ctx);
        gemm8<1><<<dim3(256), dim3(512), 0, stream>>>(
            Ctx, nullptr, nullptr, wb + 3 * WE, nullptr, nullptr, nullptr, outp);
    } else {
        unsigned short* Ctx = Vt + NE;
        gemm_k<1, 1, 0><<<dim3(1536), blk, 0, stream>>>(
            q, k, v, Wq, Wk, Wv, Qh, Kh, Vt, nullptr);
        attn_kernel<<<dim3(1024), dim3(512), 0, stream>>>(Qh, Kh, Vt, Ctx);
        gemm_k<0, 1, 1><<<dim3(512), blk, 0, stream>>>(
            Ctx, nullptr, nullptr, Wo, nullptr, nullptr,
            nullptr, nullptr, nullptr, outp);
    }
}